// Round 12
// baseline (93.193 us; speedup 1.0000x reference)
//
#include <hip/hip_runtime.h>
#include <cstdint>

#define BS 32
#define K 50000
#define K4 12500                 // K/4 uint4 per row
#define NCH 49                   // ceil(K/1024)
#define NGT 32
#define KROW (K * 5)
#define KEY_NEG1 0x407FFFFFu     // f2key(-1.0f)

__device__ __forceinline__ unsigned f2key(float f) {
    unsigned b = __float_as_uint(f);
    return (b & 0x80000000u) ? ~b : (b | 0x80000000u);
}

struct Sel { int bin; int want; int ceq; };

// Block-parallel pick: highest bin with from-top cumulative >= want.
__device__ __forceinline__ void pick256(const unsigned* __restrict__ hist_row,
                                        int want, int tid, int* T, Sel* r) {
    int h = 0;
    if (tid < 256) { h = (int)hist_row[tid]; T[tid] = h; }
    __syncthreads();
#pragma unroll
    for (int o = 1; o < 256; o <<= 1) {
        int add = 0;
        if (tid < 256) add = (tid + o < 256) ? T[tid + o] : 0;
        __syncthreads();
        if (tid < 256) T[tid] += add;
        __syncthreads();
    }
    if (tid < 256) {
        const int Ti = T[tid];
        const int Tn = (tid == 255) ? (want - 1) : T[tid + 1];
        if (Ti >= want && Tn < want) { r->bin = tid; r->ceq = h; r->want = want - (Ti - h); }
    }
    __syncthreads();
}

__device__ __forceinline__ int want_of(int np) {
    const long long w0 = 3LL * (long long)np;
    return (w0 > K) ? K : (int)w0;
}

// ------ Kernel A: ILP-4 core, VGPR-licensed pipelining, LDS gt3 broadcast ----
__global__ __launch_bounds__(256, 4) void kA(const float* __restrict__ conf,
                                             const float* __restrict__ gt,
                                             const float* __restrict__ priors,
                                             float* __restrict__ loc_t,
                                             unsigned* __restrict__ keys,
                                             unsigned* __restrict__ ghist,
                                             int* __restrict__ numpos) {
    const int b    = blockIdx.y;
    const int tid  = threadIdx.x;
    const int k0   = blockIdx.x * 1024;
    const int lane = tid & 63;
    const int rep  = tid & 7;

    __shared__ float  sb[5120];         // priors staging, reused for loc_t out
    __shared__ float  sg[NGT * 5];      // full gt rows (rare-path accumulate)
    __shared__ float4 sg3[NGT];         // (gx poisoned, gy, ga, -) per gt
    __shared__ int    lh[8][256];       // 8-replica byte-3 histogram
    __shared__ int    lpos;

    // ---- issue conf prefetch FIRST (independent; latency hidden below) ----
    const float2* c2p = (const float2*)conf + (size_t)b * K;
    float2 cf[4];
#pragma unroll
    for (int c = 0; c < 4; c++) {
        const int kk = k0 + c * 256 + tid;
        cf[c] = c2p[kk < K ? kk : K - 1];
    }

    if (tid == 0) lpos = 0;
    if (tid < NGT * 5) sg[tid] = gt[b * NGT * 5 + tid];
    if (tid < NGT) {                    // build poisoned gt3 in LDS (no kPrep)
        const float* g = gt + ((size_t)b * NGT + tid) * 5;
        const float x = g[0], y = g[1], w = g[2], h = g[3], a = g[4];
        const bool valid = !(x == 0.f && y == 0.f && w == 0.f &&
                             h == 0.f && a == 0.f);
        sg3[tid] = make_float4(valid ? x : 1e30f, y, a, 0.f);
    }
#pragma unroll
    for (int r2 = 0; r2 < 8; r2++) lh[r2][tid] = 0;

    const int ebase = k0 * 5;
    const int rem   = KROW - ebase;
    const int nf4   = (rem < 5120 ? rem : 5120) >> 2;   // float4 count
    const float4* p4 = (const float4*)(priors + (size_t)b * KROW + ebase);
#pragma unroll
    for (int j = 0; j < 5; j++) {
        const int i4 = j * 256 + tid;
        if (i4 < nf4) ((float4*)sb)[i4] = p4[i4];
    }
    __syncthreads();

    float px[4], py[4], pw[4], ph[4], pa[4];
#pragma unroll
    for (int c = 0; c < 4; c++) {
        const int l = (c * 256 + tid) * 5;   // stride-5: 2-way alias = free
        px[c] = sb[l];     py[c] = sb[l + 1]; pw[c] = sb[l + 2];
        ph[c] = sb[l + 3]; pa[c] = sb[l + 4];
    }
    __syncthreads();                     // all reads done before sb reuse

    // ---- hot loop: one broadcast ds_read_b128 per gt, 12 cmps per read ----
    unsigned mask[4] = {0u, 0u, 0u, 0u};
#pragma unroll
    for (int n = 0; n < NGT; n++) {
        const float4 g = sg3[n];              // uniform addr -> LDS broadcast
        const float gx = g.x, gy = g.y, ga = g.z;
#pragma unroll
        for (int c = 0; c < 4; c++) {
            const bool m = (fabsf(px[c] - gx) <= 16.f) &
                           (fabsf(py[c] - gy) <= 16.f) &
                           (fabsf(pa[c] - ga) <= 15.f);
            mask[c] |= m ? (1u << n) : 0u;
        }
    }

    // ---- per-c: rare accumulate (LDS gt), epilogue, key write, hist ----
#pragma unroll
    for (int c = 0; c < 4; c++) {
        const int k = k0 + c * 256 + tid;
        const bool vk = (k < K);
        const int cnt = __popc(mask[c]);
        float sx = 0.f, sy = 0.f, sw = 0.f, sh = 0.f, sa = 0.f;
        unsigned mm = mask[c];
        while (__any(mm != 0u)) {
            if (mm) {
                const int n = __ffs(mm) - 1;
                mm &= mm - 1u;
                const int base = n * 5;
                sx += sg[base];     sy += sg[base + 1]; sw += sg[base + 2];
                sh += sg[base + 3]; sa += sg[base + 4];
            }
        }
        const float inv = 1.0f / fmaxf((float)cnt, 1.0f);   // cnt==0 -> 1 exact
        const float rpw = 1.0f / pw[c], rph = 1.0f / ph[c];
        const float lx  = (sx + 1e-14f) * inv;
        const float ly  = (sy + 1e-14f) * inv;
        const float lw  = (sw + 1e-14f) * inv;
        const float lh2 = (sh + 1e-14f) * inv;
        const float la  = (sa + 1e-14f) * inv;
        const int l = (c * 256 + tid) * 5;
        sb[l]     = (lx - px[c]) * rpw * (1.0f / 0.1f);
        sb[l + 1] = (ly - py[c]) * rph * (1.0f / 0.1f);
        sb[l + 2] = __logf(lw * rpw) * (1.0f / 0.2f);
        sb[l + 3] = __logf(lh2 * rph) * (1.0f / 0.2f);
        sb[l + 4] = (la - pa[c]) * (1.0f / 0.1f);
        if (vk) {
            const float2 cc = cf[c];
            const float mmx = fmaxf(cc.x, cc.y);
            const float lse = mmx + __logf(__expf(cc.x - mmx) + __expf(cc.y - mmx));
            const float loss = (cnt > 0) ? -1.0f : (lse - cc.x);
            const unsigned key = f2key(loss);
            keys[(size_t)b * K + k] = key;
            atomicAdd(&lh[rep][key >> 24], 1);
        }
        const unsigned long long pm = __ballot(vk && (cnt > 0));
        if (lane == 0 && pm) atomicAdd(&lpos, (int)__popcll(pm));
    }
    __syncthreads();

    float4* o4 = (float4*)(loc_t + (size_t)b * KROW + ebase);
#pragma unroll
    for (int j = 0; j < 5; j++) {
        const int i4 = j * 256 + tid;
        if (i4 < nf4) o4[i4] = ((const float4*)sb)[i4];
    }
    int s = 0;
#pragma unroll
    for (int r2 = 0; r2 < 8; r2++) s += lh[r2][tid];
    if (s) atomicAdd(&ghist[b * 256 + tid], (unsigned)s);
    if (tid == 0 && lpos) atomicAdd(&numpos[b], lpos);
}

// ------ kSel: one block/row — 3 conditioned passes + finalize + tie path -----
__global__ __launch_bounds__(1024) void kSel(const unsigned* __restrict__ keys,
                                             const unsigned* __restrict__ ghist,
                                             const int* __restrict__ numpos,
                                             unsigned* __restrict__ thresh,
                                             unsigned* __restrict__ tieflag,
                                             float* __restrict__ confo) {
    const int row = blockIdx.x, tid = threadIdx.x;
    const int np = numpos[row];
    if (np <= 0) {
        if (tid == 0) { thresh[row] = 0xFFFFFFFFu; tieflag[row] = 0u; }
        return;
    }
    __shared__ int T[256];
    __shared__ Sel r;
    __shared__ int lh[4][256];
    __shared__ unsigned lhm[256];

    pick256(ghist + row * 256, want_of(np), tid, T, &r);
    unsigned pfx = (unsigned)r.bin;

    const uint4* kr4 = (const uint4*)(keys + (size_t)row * K);
#pragma unroll
    for (int level = 2; level >= 0; level--) {
        const int shift = level * 8;
        ((int*)lh)[tid] = 0;             // 1024 ints, exact cover
        __syncthreads();
        for (int i = tid; i < K4; i += 1024) {
            const uint4 kv = kr4[i];
            const unsigned ka[4] = {kv.x, kv.y, kv.z, kv.w};
#pragma unroll
            for (int j = 0; j < 4; j++)
                if ((ka[j] >> (shift + 8)) == pfx)
                    atomicAdd(&lh[tid & 3][(ka[j] >> shift) & 255u], 1);
        }
        __syncthreads();
        if (tid < 256)
            lhm[tid] = (unsigned)(lh[0][tid] + lh[1][tid] + lh[2][tid] + lh[3][tid]);
        __syncthreads();
        pick256(lhm, r.want, tid, T, &r);
        pfx = (pfx << 8) | (unsigned)r.bin;
    }

    const unsigned uT = pfx;
    const int bud = r.want;
    const bool tie = (r.want < r.ceq);
    if (tid == 0) { thresh[row] = uT; tieflag[row] = tie ? 1u : 0u; }
    if (!tie) return;

    // Rare: duplicated threshold key — rank ties in index order, write conf.
    __shared__ int wsum[16];
    __shared__ int s_run;
    if (tid == 0) s_run = 0;
    __syncthreads();
    const unsigned* kr = keys + (size_t)row * K;
    float* co = confo + (size_t)row * K;     // same region as keys: RAW per i
    for (int base = 0; base < K; base += 1024) {
        const int i = base + tid;
        const unsigned key = (i < K) ? kr[i] : 0u;
        const bool eq = (i < K) && (key == uT);
        const unsigned long long bal = __ballot(eq);
        const int lane = tid & 63, wid = tid >> 6;
        if (lane == 0) wsum[wid] = __popcll(bal);
        __syncthreads();
        if (tid == 0) {
            int acc = s_run;
            for (int w = 0; w < 16; w++) { const int t = wsum[w]; wsum[w] = acc; acc += t; }
            s_run = acc;
        }
        __syncthreads();
        if (i < K) {
            const int rank = wsum[wid] + __popcll(bal & ((1ull << lane) - 1ull));
            const bool pos = (key == KEY_NEG1);
            const bool sel = (key > uT) || (eq && rank < bud);
            co[i] = pos ? 1.0f : ((sel && !pos) ? 0.0f : -1.0f);
        }
        __syncthreads();
    }
}

// ------- D12: conf (non-tie) + iw/ow, LDS-staged coalesced stores ------------
__global__ __launch_bounds__(256) void kD12(const unsigned* __restrict__ keys,
                                            const unsigned* __restrict__ thresh,
                                            const unsigned* __restrict__ tieflag,
                                            const int* __restrict__ numpos,
                                            float* __restrict__ confo,
                                            float* __restrict__ iw,
                                            float* __restrict__ ow) {
    const int tid = threadIdx.x;
    const int g0 = blockIdx.x * 256;
    const int g = g0 + tid;                  // exact grid: no bound check
    __shared__ float si[1280];
    __shared__ float so2[1280];
    const int row = g / K;
    const unsigned key = keys[g];            // keys live in conf region
    float c;
    if (tieflag[row]) {
        c = __uint_as_float(key);            // kSel already wrote final conf
    } else {
        const unsigned uT = thresh[row];
        const bool pos = (key == KEY_NEG1);
        c = pos ? 1.0f : ((key >= uT) ? 0.0f : -1.0f);
        confo[g] = c;                        // overwrite key slot with conf
    }
    const float inv = 1.0f / (float)((numpos[row] * 4) | 1);
    const float iwv = (c == 1.0f) ? 1.0f : 0.0f;
    const float owv = (c >= 0.0f) ? inv : 0.0f;
#pragma unroll
    for (int j = 0; j < 5; j++) { si[tid * 5 + j] = iwv; so2[tid * 5 + j] = owv; }
    __syncthreads();
    const size_t e0 = (size_t)g0 * 5;
#pragma unroll
    for (int j = 0; j < 5; j++) {
        const int s = j * 256 + tid;
        iw[e0 + s] = si[s];
        ow[e0 + s] = so2[s];
    }
}

extern "C" void kernel_launch(void* const* d_in, const int* in_sizes, int n_in,
                              void* d_out, int out_size, void* d_ws, size_t ws_size,
                              hipStream_t stream) {
    const float* conf   = (const float*)d_in[0];
    const float* gt     = (const float*)d_in[1];
    const float* priors = (const float*)d_in[2];

    float* out   = (float*)d_out;
    float* loc_t = out;
    float* confo = out + 8000000;
    float* iw    = out + 9600000;
    float* ow    = out + 17600000;

    // keys live IN the conf region (same size); overwritten with conf last.
    unsigned* keys = (unsigned*)confo;
    // Small scratch in d_ws (one memset):
    int*      numpos  = (int*)d_ws;                 // 32
    unsigned* thresh  = (unsigned*)d_ws + 32;       // 32
    unsigned* tieflag = (unsigned*)d_ws + 64;       // 32
    unsigned* ghist   = (unsigned*)d_ws + 96;       // 32*256

    hipMemsetAsync(d_ws, 0, (96 + 8192) * sizeof(int), stream);

    dim3 gA(NCH, BS);                          // 49*1024 >= K priors per row
    kA<<<gA, 256, 0, stream>>>(conf, gt, priors, loc_t, keys, ghist, numpos);
    kSel<<<BS, 1024, 0, stream>>>(keys, ghist, numpos, thresh, tieflag, confo);
    kD12<<<(BS * K) / 256, 256, 0, stream>>>(keys, thresh, tieflag, numpos,
                                             confo, iw, ow);
}

// Round 13
// 90.154 us; speedup vs baseline: 1.0337x; 1.0337x over previous
//
#include <hip/hip_runtime.h>
#include <cstdint>

#define BS 32
#define K 50000
#define K4 12500                 // K/4 uint4 per row
#define NCH 49                   // ceil(K/1024)
#define NGT 32
#define KROW (K * 5)
#define KEY_NEG1 0x407FFFFFu     // f2key(-1.0f)

__device__ __forceinline__ unsigned f2key(float f) {
    unsigned b = __float_as_uint(f);
    return (b & 0x80000000u) ? ~b : (b | 0x80000000u);
}

struct Sel { int bin; int want; int ceq; };

// Block-parallel pick: highest bin with from-top cumulative >= want.
__device__ __forceinline__ void pick256(const unsigned* __restrict__ hist_row,
                                        int want, int tid, int* T, Sel* r) {
    int h = 0;
    if (tid < 256) { h = (int)hist_row[tid]; T[tid] = h; }
    __syncthreads();
#pragma unroll
    for (int o = 1; o < 256; o <<= 1) {
        int add = 0;
        if (tid < 256) add = (tid + o < 256) ? T[tid + o] : 0;
        __syncthreads();
        if (tid < 256) T[tid] += add;
        __syncthreads();
    }
    if (tid < 256) {
        const int Ti = T[tid];
        const int Tn = (tid == 255) ? (want - 1) : T[tid + 1];
        if (Ti >= want && Tn < want) { r->bin = tid; r->ceq = h; r->want = want - (Ti - h); }
    }
    __syncthreads();
}

__device__ __forceinline__ int want_of(int np) {
    const long long w0 = 3LL * (long long)np;
    return (w0 > K) ? K : (int)w0;
}

// ------ Kernel A: no staging — thread owns 4 consecutive priors --------------
__global__ __launch_bounds__(256) void kA(const float* __restrict__ conf,
                                          const float* __restrict__ gt,
                                          const float* __restrict__ priors,
                                          float* __restrict__ loc_t,
                                          unsigned* __restrict__ keys,
                                          unsigned* __restrict__ ghist,
                                          int* __restrict__ numpos) {
    const int b    = blockIdx.y;
    const int tid  = threadIdx.x;
    const int k4   = blockIdx.x * 1024 + tid * 4;   // first of 4 owned priors
    const int lane = tid & 63;
    const int rep  = tid & 7;

    __shared__ float sg[NGT * 5];
    __shared__ int   lh[8][256];
    __shared__ int   lpos;

    if (tid < NGT * 5) sg[tid] = gt[b * NGT * 5 + tid];
#pragma unroll
    for (int r2 = 0; r2 < 8; r2++) lh[r2][tid] = 0;
    if (tid == 0) lpos = 0;
    __syncthreads();

    const bool vk = (k4 < K);            // K%4==0 -> whole thread in or out

    // ---- direct global loads: 5 float4 (priors) + 2 float4 (conf) ----
    float p[20];                         // 4 priors, reused for outputs
    float cf[8];
    if (vk) {
        const float4* pp = (const float4*)(priors + (size_t)b * KROW + (size_t)k4 * 5);
#pragma unroll
        for (int j = 0; j < 5; j++) ((float4*)p)[j] = pp[j];
        const float4* cp = (const float4*)(conf + ((size_t)b * K + k4) * 2);
        ((float4*)cf)[0] = cp[0];
        ((float4*)cf)[1] = cp[1];
    }

    // ---- hot loop: wave-uniform scalar gt loads, 12 cmps per gt ----
    const unsigned* gtu = (const unsigned*)(gt + (size_t)b * NGT * 5);
    unsigned mask[4] = {0u, 0u, 0u, 0u};
#pragma unroll
    for (int n = 0; n < NGT; n++) {
        const unsigned ux = gtu[n * 5],     uy = gtu[n * 5 + 1],
                       uw = gtu[n * 5 + 2], uh = gtu[n * 5 + 3],
                       ua = gtu[n * 5 + 4];
        const bool gvalid = ((ux | uy | uw | uh | ua) != 0u);      // SALU
        const float gx = gvalid ? __uint_as_float(ux) : 1e30f;     // poison
        const float gy = __uint_as_float(uy);
        const float ga = __uint_as_float(ua);
#pragma unroll
        for (int c = 0; c < 4; c++) {
            const bool m = (fabsf(p[c * 5]     - gx) <= 16.f) &
                           (fabsf(p[c * 5 + 1] - gy) <= 16.f) &
                           (fabsf(p[c * 5 + 4] - ga) <= 15.f);
            mask[c] |= m ? (1u << n) : 0u;
        }
    }

    // ---- per-c: rare accumulate (LDS gt), epilogue in-place, key ----
    unsigned keyv[4];
    int npos = 0;
#pragma unroll
    for (int c = 0; c < 4; c++) {
        const int cnt = __popc(mask[c]);
        float sx = 0.f, sy = 0.f, sw = 0.f, sh = 0.f, sa = 0.f;
        unsigned mm = mask[c];
        while (__any(mm != 0u)) {
            if (mm) {
                const int n = __ffs(mm) - 1;
                mm &= mm - 1u;
                const int base = n * 5;
                sx += sg[base];     sy += sg[base + 1]; sw += sg[base + 2];
                sh += sg[base + 3]; sa += sg[base + 4];
            }
        }
        const float px = p[c * 5],     py = p[c * 5 + 1], pw = p[c * 5 + 2],
                    ph = p[c * 5 + 3], pa = p[c * 5 + 4];
        const float inv = 1.0f / fmaxf((float)cnt, 1.0f);   // cnt==0 -> 1 exact
        const float rpw = 1.0f / pw, rph = 1.0f / ph;
        const float lx  = (sx + 1e-14f) * inv;
        const float ly  = (sy + 1e-14f) * inv;
        const float lw  = (sw + 1e-14f) * inv;
        const float lh2 = (sh + 1e-14f) * inv;
        const float la  = (sa + 1e-14f) * inv;
        p[c * 5]     = (lx - px) * rpw * (1.0f / 0.1f);
        p[c * 5 + 1] = (ly - py) * rph * (1.0f / 0.1f);
        p[c * 5 + 2] = __logf(lw * rpw) * (1.0f / 0.2f);
        p[c * 5 + 3] = __logf(lh2 * rph) * (1.0f / 0.2f);
        p[c * 5 + 4] = (la - pa) * (1.0f / 0.1f);

        const float c0 = cf[c * 2], c1 = cf[c * 2 + 1];
        const float mmx = fmaxf(c0, c1);
        const float lse = mmx + __logf(__expf(c0 - mmx) + __expf(c1 - mmx));
        const float loss = (cnt > 0) ? -1.0f : (lse - c0);
        keyv[c] = f2key(loss);
        npos += (cnt > 0) ? 1 : 0;
        if (vk) atomicAdd(&lh[rep][keyv[c] >> 24], 1);
    }

    // ---- direct global stores: uint4 keys + 5 float4 loc_t ----
    if (vk) {
        *(uint4*)(keys + (size_t)b * K + k4) =
            make_uint4(keyv[0], keyv[1], keyv[2], keyv[3]);
        float4* o4 = (float4*)(loc_t + (size_t)b * KROW + (size_t)k4 * 5);
#pragma unroll
        for (int j = 0; j < 5; j++) o4[j] = ((const float4*)p)[j];
    }

    // numpos: per-wave sum of per-thread counts (0..4) via 3 ballots
    int wsum = 0;
#pragma unroll
    for (int bit = 0; bit < 3; bit++) {
        const unsigned long long bm = __ballot(vk && ((npos >> bit) & 1));
        wsum += __popcll(bm) << bit;
    }
    if (lane == 0 && wsum) atomicAdd(&lpos, wsum);
    __syncthreads();

    int s = 0;
#pragma unroll
    for (int r2 = 0; r2 < 8; r2++) s += lh[r2][tid];
    if (s) atomicAdd(&ghist[b * 256 + tid], (unsigned)s);
    if (tid == 0 && lpos) atomicAdd(&numpos[b], lpos);
}

// ------ kSel: one block/row — 3 conditioned passes + finalize + tie path -----
__global__ __launch_bounds__(1024) void kSel(const unsigned* __restrict__ keys,
                                             const unsigned* __restrict__ ghist,
                                             const int* __restrict__ numpos,
                                             unsigned* __restrict__ thresh,
                                             unsigned* __restrict__ tieflag,
                                             float* __restrict__ confo) {
    const int row = blockIdx.x, tid = threadIdx.x;
    const int np = numpos[row];
    if (np <= 0) {
        if (tid == 0) { thresh[row] = 0xFFFFFFFFu; tieflag[row] = 0u; }
        return;
    }
    __shared__ int T[256];
    __shared__ Sel r;
    __shared__ int lh[4][256];
    __shared__ unsigned lhm[256];

    pick256(ghist + row * 256, want_of(np), tid, T, &r);
    unsigned pfx = (unsigned)r.bin;

    const uint4* kr4 = (const uint4*)(keys + (size_t)row * K);
#pragma unroll
    for (int level = 2; level >= 0; level--) {
        const int shift = level * 8;
        ((int*)lh)[tid] = 0;             // 1024 ints, exact cover
        __syncthreads();
        for (int i = tid; i < K4; i += 1024) {
            const uint4 kv = kr4[i];
            const unsigned ka[4] = {kv.x, kv.y, kv.z, kv.w};
#pragma unroll
            for (int j = 0; j < 4; j++)
                if ((ka[j] >> (shift + 8)) == pfx)
                    atomicAdd(&lh[tid & 3][(ka[j] >> shift) & 255u], 1);
        }
        __syncthreads();
        if (tid < 256)
            lhm[tid] = (unsigned)(lh[0][tid] + lh[1][tid] + lh[2][tid] + lh[3][tid]);
        __syncthreads();
        pick256(lhm, r.want, tid, T, &r);
        pfx = (pfx << 8) | (unsigned)r.bin;
    }

    const unsigned uT = pfx;
    const int bud = r.want;
    const bool tie = (r.want < r.ceq);
    if (tid == 0) { thresh[row] = uT; tieflag[row] = tie ? 1u : 0u; }
    if (!tie) return;

    // Rare: duplicated threshold key — rank ties in index order, write conf.
    __shared__ int wsum[16];
    __shared__ int s_run;
    if (tid == 0) s_run = 0;
    __syncthreads();
    const unsigned* kr = keys + (size_t)row * K;
    float* co = confo + (size_t)row * K;     // same region as keys: RAW per i
    for (int base = 0; base < K; base += 1024) {
        const int i = base + tid;
        const unsigned key = (i < K) ? kr[i] : 0u;
        const bool eq = (i < K) && (key == uT);
        const unsigned long long bal = __ballot(eq);
        const int lane = tid & 63, wid = tid >> 6;
        if (lane == 0) wsum[wid] = __popcll(bal);
        __syncthreads();
        if (tid == 0) {
            int acc = s_run;
            for (int w = 0; w < 16; w++) { const int t = wsum[w]; wsum[w] = acc; acc += t; }
            s_run = acc;
        }
        __syncthreads();
        if (i < K) {
            const int rank = wsum[wid] + __popcll(bal & ((1ull << lane) - 1ull));
            const bool pos = (key == KEY_NEG1);
            const bool sel = (key > uT) || (eq && rank < bud);
            co[i] = pos ? 1.0f : ((sel && !pos) ? 0.0f : -1.0f);
        }
        __syncthreads();
    }
}

// ------- D12: no LDS — thread owns 4 consecutive priors ----------------------
__global__ __launch_bounds__(256) void kD12(const unsigned* __restrict__ keys,
                                            const unsigned* __restrict__ thresh,
                                            const unsigned* __restrict__ tieflag,
                                            const int* __restrict__ numpos,
                                            float* __restrict__ confo,
                                            float* __restrict__ iw,
                                            float* __restrict__ ow) {
    const int t = blockIdx.x * 256 + threadIdx.x;
    const int g4 = t * 4;                   // 4 consecutive priors (one row)
    if (g4 >= BS * K) return;
    const int row = g4 / K;
    const uint4 kv = *(const uint4*)(keys + g4);
    const unsigned ka[4] = {kv.x, kv.y, kv.z, kv.w};
    const unsigned uT = thresh[row];
    const unsigned tf = tieflag[row];
    const float inv = 1.0f / (float)((numpos[row] * 4) | 1);
    float c[4], iwv[20], owv[20];
#pragma unroll
    for (int j = 0; j < 4; j++) {
        if (tf) {
            c[j] = __uint_as_float(ka[j]);  // kSel wrote final conf here
        } else {
            const bool pos = (ka[j] == KEY_NEG1);
            c[j] = pos ? 1.0f : ((ka[j] >= uT) ? 0.0f : -1.0f);
        }
        const float iv = (c[j] == 1.0f) ? 1.0f : 0.0f;
        const float ov = (c[j] >= 0.0f) ? inv : 0.0f;
#pragma unroll
        for (int e = 0; e < 5; e++) { iwv[j * 5 + e] = iv; owv[j * 5 + e] = ov; }
    }
    if (!tf) *(float4*)(confo + g4) = make_float4(c[0], c[1], c[2], c[3]);
    float4* i4 = (float4*)(iw + (size_t)g4 * 5);
    float4* o4 = (float4*)(ow + (size_t)g4 * 5);
#pragma unroll
    for (int j = 0; j < 5; j++) {
        i4[j] = ((const float4*)iwv)[j];
        o4[j] = ((const float4*)owv)[j];
    }
}

extern "C" void kernel_launch(void* const* d_in, const int* in_sizes, int n_in,
                              void* d_out, int out_size, void* d_ws, size_t ws_size,
                              hipStream_t stream) {
    const float* conf   = (const float*)d_in[0];
    const float* gt     = (const float*)d_in[1];
    const float* priors = (const float*)d_in[2];

    float* out   = (float*)d_out;
    float* loc_t = out;
    float* confo = out + 8000000;
    float* iw    = out + 9600000;
    float* ow    = out + 17600000;

    // keys live IN the conf region (same size); overwritten with conf last.
    unsigned* keys = (unsigned*)confo;
    // Small scratch in d_ws (one memset):
    int*      numpos  = (int*)d_ws;                 // 32
    unsigned* thresh  = (unsigned*)d_ws + 32;       // 32
    unsigned* tieflag = (unsigned*)d_ws + 64;       // 32
    unsigned* ghist   = (unsigned*)d_ws + 96;       // 32*256

    hipMemsetAsync(d_ws, 0, (96 + 8192) * sizeof(int), stream);

    dim3 gA(NCH, BS);                          // 49*1024 >= K priors per row
    kA<<<gA, 256, 0, stream>>>(conf, gt, priors, loc_t, keys, ghist, numpos);
    kSel<<<BS, 1024, 0, stream>>>(keys, ghist, numpos, thresh, tieflag, confo);
    kD12<<<(BS * K / 4 + 255) / 256, 256, 0, stream>>>(keys, thresh, tieflag,
                                                       numpos, confo, iw, ow);
}

// Round 14
// 66.112 us; speedup vs baseline: 1.4096x; 1.3636x over previous
//
#include <hip/hip_runtime.h>
#include <cstdint>

#define BS 32
#define K 50000
#define K4 12500                 // K/4 uint4 per row
#define NCH 49                   // ceil(K/1024)
#define NGT 32
#define KROW (K * 5)
#define KEY_NEG1 0x407FFFFFu     // f2key(-1.0f)

__device__ __forceinline__ unsigned f2key(float f) {
    unsigned b = __float_as_uint(f);
    return (b & 0x80000000u) ? ~b : (b | 0x80000000u);
}

struct Sel { int bin; int want; int ceq; };

// Block-parallel pick: highest bin with from-top cumulative >= want.
__device__ __forceinline__ void pick256(const unsigned* __restrict__ hist_row,
                                        int want, int tid, int* T, Sel* r) {
    int h = 0;
    if (tid < 256) { h = (int)hist_row[tid]; T[tid] = h; }
    __syncthreads();
#pragma unroll
    for (int o = 1; o < 256; o <<= 1) {
        int add = 0;
        if (tid < 256) add = (tid + o < 256) ? T[tid + o] : 0;
        __syncthreads();
        if (tid < 256) T[tid] += add;
        __syncthreads();
    }
    if (tid < 256) {
        const int Ti = T[tid];
        const int Tn = (tid == 255) ? (want - 1) : T[tid + 1];
        if (Ti >= want && Tn < want) { r->bin = tid; r->ceq = h; r->want = want - (Ti - h); }
    }
    __syncthreads();
}

__device__ __forceinline__ int want_of(int np) {
    const long long w0 = 3LL * (long long)np;
    return (w0 > K) ? K : (int)w0;
}

// ------ Kernel A: r9 structure + conf hoist + per-chunk hist stores ----------
__global__ __launch_bounds__(256) void kA(const float* __restrict__ conf,
                                          const float* __restrict__ gt,
                                          const float* __restrict__ priors,
                                          float* __restrict__ loc_t,
                                          unsigned* __restrict__ keys,
                                          unsigned* __restrict__ ghist_part,
                                          unsigned* __restrict__ npos_part) {
    const int b    = blockIdx.y;
    const int tid  = threadIdx.x;
    const int k0   = blockIdx.x * 1024;
    const int lane = tid & 63;
    const int rep  = tid & 7;

    __shared__ float sb[5120];          // priors staging, reused for loc_t out
    __shared__ float sg[NGT * 5];
    __shared__ int   lh[8][256];        // 8-replica byte-3 histogram
    __shared__ int   lpos;

    if (tid == 0) lpos = 0;
    if (tid < NGT * 5) sg[tid] = gt[b * NGT * 5 + tid];
#pragma unroll
    for (int r2 = 0; r2 < 8; r2++) lh[r2][tid] = 0;

    const int ebase = k0 * 5;
    const int rem   = KROW - ebase;
    const int nf4   = (rem < 5120 ? rem : 5120) >> 2;   // float4 count
    const float4* p4 = (const float4*)(priors + (size_t)b * KROW + ebase);
#pragma unroll
    for (int j = 0; j < 5; j++) {
        const int i4 = j * 256 + tid;
        if (i4 < nf4) ((float4*)sb)[i4] = p4[i4];
    }
    __syncthreads();

    float px[4], py[4], pw[4], ph[4], pa[4];
#pragma unroll
    for (int c = 0; c < 4; c++) {
        const int l = (c * 256 + tid) * 5;   // stride-5: 2-way alias = free
        px[c] = sb[l];     py[c] = sb[l + 1]; pw[c] = sb[l + 2];
        ph[c] = sb[l + 3]; pa[c] = sb[l + 4];
    }
    __syncthreads();                     // all reads done before sb reuse

    // ---- conf prefetch: independent, latency hidden under the mask loop ----
    const float2* c2p = (const float2*)conf + (size_t)b * K;
    float2 cf[4];
#pragma unroll
    for (int c = 0; c < 4; c++) {
        const int kk = k0 + c * 256 + tid;
        cf[c] = c2p[kk < K ? kk : K - 1];
    }

    // ---- hot loop: wave-uniform scalar gt loads, 12 cmps per gt ----
    const unsigned* gtu = (const unsigned*)(gt + (size_t)b * NGT * 5);
    unsigned mask[4] = {0u, 0u, 0u, 0u};
#pragma unroll
    for (int n = 0; n < NGT; n++) {
        const unsigned ux = gtu[n * 5],     uy = gtu[n * 5 + 1],
                       uw = gtu[n * 5 + 2], uh = gtu[n * 5 + 3],
                       ua = gtu[n * 5 + 4];
        const bool gvalid = ((ux | uy | uw | uh | ua) != 0u);      // SALU
        const float gx = gvalid ? __uint_as_float(ux) : 1e30f;     // poison
        const float gy = __uint_as_float(uy);
        const float ga = __uint_as_float(ua);
#pragma unroll
        for (int c = 0; c < 4; c++) {
            const bool m = (fabsf(px[c] - gx) <= 16.f) &
                           (fabsf(py[c] - gy) <= 16.f) &
                           (fabsf(pa[c] - ga) <= 15.f);
            mask[c] |= m ? (1u << n) : 0u;
        }
    }

    // ---- per-c: rare accumulate (LDS gt), epilogue, key write, hist ----
#pragma unroll
    for (int c = 0; c < 4; c++) {
        const int k = k0 + c * 256 + tid;
        const bool vk = (k < K);
        const int cnt = __popc(mask[c]);
        float sx = 0.f, sy = 0.f, sw = 0.f, sh = 0.f, sa = 0.f;
        unsigned mm = mask[c];
        while (__any(mm != 0u)) {
            if (mm) {
                const int n = __ffs(mm) - 1;
                mm &= mm - 1u;
                const int base = n * 5;
                sx += sg[base];     sy += sg[base + 1]; sw += sg[base + 2];
                sh += sg[base + 3]; sa += sg[base + 4];
            }
        }
        const float inv = 1.0f / fmaxf((float)cnt, 1.0f);   // cnt==0 -> 1 exact
        const float rpw = 1.0f / pw[c], rph = 1.0f / ph[c];
        const float lx  = (sx + 1e-14f) * inv;
        const float ly  = (sy + 1e-14f) * inv;
        const float lw  = (sw + 1e-14f) * inv;
        const float lh2 = (sh + 1e-14f) * inv;
        const float la  = (sa + 1e-14f) * inv;
        const int l = (c * 256 + tid) * 5;
        sb[l]     = (lx - px[c]) * rpw * (1.0f / 0.1f);
        sb[l + 1] = (ly - py[c]) * rph * (1.0f / 0.1f);
        sb[l + 2] = __logf(lw * rpw) * (1.0f / 0.2f);
        sb[l + 3] = __logf(lh2 * rph) * (1.0f / 0.2f);
        sb[l + 4] = (la - pa[c]) * (1.0f / 0.1f);
        if (vk) {
            const float2 cc = cf[c];
            const float mmx = fmaxf(cc.x, cc.y);
            const float lse = mmx + __logf(__expf(cc.x - mmx) + __expf(cc.y - mmx));
            const float loss = (cnt > 0) ? -1.0f : (lse - cc.x);
            const unsigned key = f2key(loss);
            keys[(size_t)b * K + k] = key;
            atomicAdd(&lh[rep][key >> 24], 1);
        }
        const unsigned long long pm = __ballot(vk && (cnt > 0));
        if (lane == 0 && pm) atomicAdd(&lpos, (int)__popcll(pm));
    }
    __syncthreads();

    float4* o4 = (float4*)(loc_t + (size_t)b * KROW + ebase);
#pragma unroll
    for (int j = 0; j < 5; j++) {
        const int i4 = j * 256 + tid;
        if (i4 < nf4) o4[i4] = ((const float4*)sb)[i4];
    }
    // Per-chunk partial outputs: plain stores, no zero-init needed.
    int s = 0;
#pragma unroll
    for (int r2 = 0; r2 < 8; r2++) s += lh[r2][tid];
    ghist_part[((size_t)b * NCH + blockIdx.x) * 256 + tid] = (unsigned)s;
    if (tid == 0) npos_part[b * NCH + blockIdx.x] = (unsigned)lpos;
}

// ------ kSel: sum parts, 3 conditioned passes + finalize + tie path ----------
__global__ __launch_bounds__(1024) void kSel(const unsigned* __restrict__ keys,
                                             const unsigned* __restrict__ ghist_part,
                                             const unsigned* __restrict__ npos_part,
                                             int* __restrict__ numpos,
                                             unsigned* __restrict__ thresh,
                                             unsigned* __restrict__ tieflag,
                                             float* __restrict__ confo) {
    const int row = blockIdx.x, tid = threadIdx.x;
    __shared__ int T[256];
    __shared__ Sel r;
    __shared__ int lh[4][256];
    __shared__ unsigned lhm[256];
    __shared__ int s_np;

    if (tid == 0) s_np = 0;
    __syncthreads();
    if (tid < NCH) atomicAdd(&s_np, (int)npos_part[row * NCH + tid]);
    if (tid < 256) {
        unsigned acc = 0;
        for (int c = 0; c < NCH; c++)
            acc += ghist_part[((size_t)row * NCH + c) * 256 + tid];
        lhm[tid] = acc;
    }
    __syncthreads();
    const int np = s_np;
    if (tid == 0) numpos[row] = np;
    if (np <= 0) {
        if (tid == 0) { thresh[row] = 0xFFFFFFFFu; tieflag[row] = 0u; }
        return;
    }

    pick256(lhm, want_of(np), tid, T, &r);
    unsigned pfx = (unsigned)r.bin;

    const uint4* kr4 = (const uint4*)(keys + (size_t)row * K);
#pragma unroll
    for (int level = 2; level >= 0; level--) {
        const int shift = level * 8;
        ((int*)lh)[tid] = 0;             // 1024 ints, exact cover
        __syncthreads();
        for (int i = tid; i < K4; i += 1024) {
            const uint4 kv = kr4[i];
            const unsigned ka[4] = {kv.x, kv.y, kv.z, kv.w};
#pragma unroll
            for (int j = 0; j < 4; j++)
                if ((ka[j] >> (shift + 8)) == pfx)
                    atomicAdd(&lh[tid & 3][(ka[j] >> shift) & 255u], 1);
        }
        __syncthreads();
        if (tid < 256)
            lhm[tid] = (unsigned)(lh[0][tid] + lh[1][tid] + lh[2][tid] + lh[3][tid]);
        __syncthreads();
        pick256(lhm, r.want, tid, T, &r);
        pfx = (pfx << 8) | (unsigned)r.bin;
    }

    const unsigned uT = pfx;
    const int bud = r.want;
    const bool tie = (r.want < r.ceq);
    if (tid == 0) { thresh[row] = uT; tieflag[row] = tie ? 1u : 0u; }
    if (!tie) return;

    // Rare: duplicated threshold key — rank ties in index order, write conf.
    __shared__ int wsum[16];
    __shared__ int s_run;
    if (tid == 0) s_run = 0;
    __syncthreads();
    const unsigned* kr = keys + (size_t)row * K;
    float* co = confo + (size_t)row * K;     // same region as keys: RAW per i
    for (int base = 0; base < K; base += 1024) {
        const int i = base + tid;
        const unsigned key = (i < K) ? kr[i] : 0u;
        const bool eq = (i < K) && (key == uT);
        const unsigned long long bal = __ballot(eq);
        const int lane = tid & 63, wid = tid >> 6;
        if (lane == 0) wsum[wid] = __popcll(bal);
        __syncthreads();
        if (tid == 0) {
            int acc = s_run;
            for (int w = 0; w < 16; w++) { const int t = wsum[w]; wsum[w] = acc; acc += t; }
            s_run = acc;
        }
        __syncthreads();
        if (i < K) {
            const int rank = wsum[wid] + __popcll(bal & ((1ull << lane) - 1ull));
            const bool pos = (key == KEY_NEG1);
            const bool sel = (key > uT) || (eq && rank < bud);
            co[i] = pos ? 1.0f : ((sel && !pos) ? 0.0f : -1.0f);
        }
        __syncthreads();
    }
}

// ------- D12: conf (non-tie) + iw/ow, LDS-staged coalesced stores ------------
__global__ __launch_bounds__(256) void kD12(const unsigned* __restrict__ keys,
                                            const unsigned* __restrict__ thresh,
                                            const unsigned* __restrict__ tieflag,
                                            const int* __restrict__ numpos,
                                            float* __restrict__ confo,
                                            float* __restrict__ iw,
                                            float* __restrict__ ow) {
    const int tid = threadIdx.x;
    const int g0 = blockIdx.x * 256;
    const int g = g0 + tid;                  // exact grid: no bound check
    __shared__ float si[1280];
    __shared__ float so2[1280];
    const int row = g / K;
    const unsigned key = keys[g];            // keys live in conf region
    float c;
    if (tieflag[row]) {
        c = __uint_as_float(key);            // kSel already wrote final conf
    } else {
        const unsigned uT = thresh[row];
        const bool pos = (key == KEY_NEG1);
        c = pos ? 1.0f : ((key >= uT) ? 0.0f : -1.0f);
        confo[g] = c;                        // overwrite key slot with conf
    }
    const float inv = 1.0f / (float)((numpos[row] * 4) | 1);
    const float iwv = (c == 1.0f) ? 1.0f : 0.0f;
    const float owv = (c >= 0.0f) ? inv : 0.0f;
#pragma unroll
    for (int j = 0; j < 5; j++) { si[tid * 5 + j] = iwv; so2[tid * 5 + j] = owv; }
    __syncthreads();
    const size_t e0 = (size_t)g0 * 5;
#pragma unroll
    for (int j = 0; j < 5; j++) {
        const int s = j * 256 + tid;
        iw[e0 + s] = si[s];
        ow[e0 + s] = so2[s];
    }
}

extern "C" void kernel_launch(void* const* d_in, const int* in_sizes, int n_in,
                              void* d_out, int out_size, void* d_ws, size_t ws_size,
                              hipStream_t stream) {
    const float* conf   = (const float*)d_in[0];
    const float* gt     = (const float*)d_in[1];
    const float* priors = (const float*)d_in[2];

    float* out   = (float*)d_out;
    float* loc_t = out;
    float* confo = out + 8000000;
    float* iw    = out + 9600000;
    float* ow    = out + 17600000;

    // keys live IN the conf region (same size); overwritten with conf last.
    unsigned* keys = (unsigned*)confo;
    // Per-chunk partials in ow region (plain-stored by kA, read by kSel,
    // clobbered only by kD12 at the very end). No memset needed anywhere.
    unsigned* owu        = (unsigned*)ow;
    unsigned* ghist_part = owu;                      // 32*49*256 = 401,408
    unsigned* npos_part  = owu + 401408;             // 32*49 = 1,568
    // Final per-row scalars in d_ws (all written unconditionally by kSel):
    int*      numpos  = (int*)d_ws;                  // 32
    unsigned* thresh  = (unsigned*)d_ws + 32;        // 32
    unsigned* tieflag = (unsigned*)d_ws + 64;        // 32

    dim3 gA(NCH, BS);                          // 49*1024 >= K priors per row
    kA<<<gA, 256, 0, stream>>>(conf, gt, priors, loc_t, keys,
                               ghist_part, npos_part);
    kSel<<<BS, 1024, 0, stream>>>(keys, ghist_part, npos_part, numpos,
                                  thresh, tieflag, confo);
    kD12<<<(BS * K) / 256, 256, 0, stream>>>(keys, thresh, tieflag, numpos,
                                             confo, iw, ow);
}